// Round 3
// baseline (663.652 us; speedup 1.0000x reference)
//
#include <hip/hip_runtime.h>

// Pruned RNN-T loss forward. B=8, T=192, U=193, V=512, PRUNE=5.
// Band row t: u in [t-5, t+5] ∩ [0, tlen]; lane d <-> u = t-5+d (d in 0..10).
//
// v3 (resubmit — round 2 was a container infra failure, no kernel evidence):
// single fused kernel. One block per batch element:
//   phase 1: 896 threads gather the whole band into LDS.
//   phase 2: 55 sixteen-lane DPP engines = 5 chunks x 11 basis columns run the
//            verified row update on basis vectors (depth 39 rows) -> 11x11
//            chunk transfer matrices in LDS.
//   phase 3: wave 0 computes row 0, folds the 5 matrices ((lse,+) matvec,
//            lae2 tree over 11 terms) and emits the loss.
// Removes vs v2: workspace round-trip, one kernel launch, global-latency fold.
// Per-row math identical to the harness-verified kernels; only chunk-boundary
// reassociation differs (few-ulp scale).

#define NEGV -1.0e30f
#define LOG2E 1.4426950408889634f
#define LN2   0.6931471805599453f

constexpr int Bc = 8, Tc = 192, Uc = 193, Vc = 512;
constexpr int Utc = Uc - 1;   // 192
constexpr int ROWS = Tc + 1;  // 193
constexpr int NCH = 5;        // chunks covering rows 1..192
constexpr int CL  = 39;       // ceil(192 / NCH); last chunk is short
constexpr int NTHR = 896;     // 14 waves = 56 engines (55 used)

#if __has_builtin(__builtin_amdgcn_exp2f)
#define EXP2(x) __builtin_amdgcn_exp2f(x)
#else
#define EXP2(x) __expf((x) * LN2)
#endif
#if __has_builtin(__builtin_amdgcn_logf)
#define LOG2(x) __builtin_amdgcn_logf(x)
#else
#define LOG2(x) (__logf(x) * LOG2E)
#endif

// result = valid_src ? src[lane mapped by CTRL] : old   (bound_ctrl=0)
// row_shr:N (lane i <- i-N within 16-lane row): CTRL = 0x110+N
// row_shl:1 (lane i <- i+1 within row):         CTRL = 0x101
template <int CTRL>
__device__ __forceinline__ float dppf(float old, float x) {
    return __int_as_float(__builtin_amdgcn_update_dpp(
        __float_as_int(old), __float_as_int(x), CTRL, 0xF, 0xF, false));
}

// log2-domain logaddexp: values are ln(p)*log2(e); exp2(-1.4e30-x)==0 exactly.
__device__ __forceinline__ float lae2(float a, float b) {
    float m = fmaxf(a, b);
    float d = fminf(a, b) - m;
    return m + LOG2(1.0f + EXP2(d));
}

__device__ __forceinline__ float prefix_sum16(float g) {
    g += dppf<0x111>(0.0f, g);
    g += dppf<0x112>(0.0f, g);
    g += dppf<0x114>(0.0f, g);
    g += dppf<0x118>(0.0f, g);
    return g;
}

__device__ __forceinline__ float prefix_lae16(float s) {
    s = lae2(dppf<0x111>(NEGV, s), s);
    s = lae2(dppf<0x112>(NEGV, s), s);
    s = lae2(dppf<0x114>(NEGV, s), s);
    s = lae2(dppf<0x118>(NEGV, s), s);
    return s;
}

// One verified row update: alpha_{t-1} (d-coords of row t-1) -> alpha_t.
__device__ __forceinline__ float row_update(float alpha, float2 cur, int t,
                                            int tlen, int ls) {
    float base = dppf<0x101>(NEGV, alpha) + cur.x;  // blank move, band shift by 1
    float res;
    if (t == Tc) {
        res = base;                  // row T: emit gains are -inf in the reference
    } else {
        float G = prefix_sum16(cur.y);
        res = prefix_lae16(base - G) + G;  // r[d]=G[d]+prefix-lae(base[k]-G[k])
    }
    int u = t - 5 + ls;
    bool valid = (ls <= 10) && (u >= 0) && (u <= tlen);
    return valid ? res : NEGV;
}

__global__ void __launch_bounds__(NTHR) rnnt_fused_kernel(
        const float* __restrict__ lp, const int* __restrict__ targets,
        const int* __restrict__ logit_len, const int* __restrict__ target_len,
        float* __restrict__ out) {
    __shared__ float2 rowbuf[ROWS * 16];   // [t][d] = {blank into (t,u), emit gain} * log2e
    __shared__ float  mat[NCH * 11 * 16];  // chunk transfer matrices, column-major per chunk

    const int b = blockIdx.x;
    const int llen = logit_len[b];
    const int tlen = target_len[b];
    const int nrows = llen + 1;

    // ---- phase 1: gather band cells straight into LDS ----
    for (int idx = threadIdx.x; idx < nrows * 16; idx += NTHR) {
        int t = idx >> 4, d = idx & 15;
        int u = t - 5 + d;
        float bl = NEGV;  // blank move into (t,u) from (t-1,u): lp[b,t-1,u,0]
        float g = 0.0f;   // emit gain into (t,u) from (t,u-1)
        if (d <= 10 && u >= 0 && u <= Uc - 1 && t >= 1)
            bl = lp[(((size_t)b * Tc + (t - 1)) * Uc + u) * Vc] * LOG2E;
        if (d <= 10 && u >= 1 && u <= Uc - 1 && t <= Tc - 1)
            g = lp[(((size_t)b * Tc + t) * Uc + (u - 1)) * Vc
                   + targets[b * Utc + (u - 1)]] * LOG2E;
        rowbuf[idx] = make_float2(bl, g);
    }
    __syncthreads();

    // ---- phase 2: per-chunk 11x11 transfer matrices (basis propagation) ----
    const int e  = threadIdx.x >> 4;  // engine id
    const int ls = threadIdx.x & 15;  // d within the band
    if (e < NCH * 11) {
        const int c = e / 11, j = e - c * 11;  // chunk, basis column
        const int t0 = 1 + c * CL;
        const int tend = min(t0 + CL - 1, llen);
        float alpha = (ls == j) ? 0.0f : NEGV;  // basis e_j; inactive chunks -> identity
        for (int t = t0; t <= tend; ++t)
            alpha = row_update(alpha, rowbuf[t * 16 + ls], t, tlen, ls);
        mat[e * 16 + ls] = alpha;
    }
    __syncthreads();

    if (threadIdx.x >= 64) return;

    // ---- phase 3 (wave 0): row 0, then fold chunk matrices ----
    float v;
    {
        float2 cur = rowbuf[ls];           // row 0
        float G = prefix_sum16(cur.y);
        float base = (ls == 5) ? 0.0f : NEGV;  // alpha[0,0] = 0 at u=0 (d=5)
        float r = prefix_lae16(base - G) + G;
        int u = ls - 5;
        v = (ls <= 10 && u >= 0 && u <= tlen) ? r : NEGV;
    }

    // v_new[d] = lse_j( M_c[d][j] + v[j] ), c = 0..4 sequentially
    for (int c = 0; c < NCH; ++c) {
        float cand[11];
        #pragma unroll
        for (int jj = 0; jj < 11; ++jj) {
            float m = mat[(c * 11 + jj) * 16 + ls];
            float vj = __int_as_float(
                __builtin_amdgcn_readlane(__float_as_int(v), jj));
            cand[jj] = m + vj;
        }
        float a0 = lae2(cand[0], cand[1]);
        float a1 = lae2(cand[2], cand[3]);
        float a2 = lae2(cand[4], cand[5]);
        float a3 = lae2(cand[6], cand[7]);
        float a4 = lae2(cand[8], cand[9]);
        float b0 = lae2(a0, a1);
        float b1 = lae2(a2, a3);
        float b2 = lae2(a4, cand[10]);
        v = lae2(lae2(b0, b1), b2);
    }

    // v holds row llen; terminal cell u=tlen lives in lane tlen-llen+5
    if ((int)threadIdx.x == tlen - llen + 5)
        atomicAdd(out, v * (-LN2 / (float)Bc));  // back to natural log + mean
}

extern "C" void kernel_launch(void* const* d_in, const int* in_sizes, int n_in,
                              void* d_out, int out_size, void* d_ws, size_t ws_size,
                              hipStream_t stream) {
    const float* lp    = (const float*)d_in[0];
    const int* targets = (const int*)d_in[1];
    const int* llen    = (const int*)d_in[2];
    const int* tlen    = (const int*)d_in[3];
    float* out = (float*)d_out;

    hipMemsetAsync(out, 0, sizeof(float) * out_size, stream);
    rnnt_fused_kernel<<<Bc, NTHR, 0, stream>>>(lp, targets, llen, tlen, out);
}